// Round 8
// baseline (718.606 us; speedup 1.0000x reference)
//
#include <hip/hip_runtime.h>

#define N_NODES 50000
#define N_EDGES 600000
#define DIM 128
#define HID 256
#define MR 32            // rows (edges/nodes) per block

typedef float  f32x4  __attribute__((ext_vector_type(4), aligned(16), may_alias));
typedef float  f32x2  __attribute__((ext_vector_type(2), aligned(8),  may_alias));
typedef __bf16 bf16x8 __attribute__((ext_vector_type(8), aligned(16), may_alias));

static __device__ inline f32x4 mfma16x16x32(bf16x8 a, bf16x8 b, f32x4 c) {
    return __builtin_amdgcn_mfma_f32_16x16x32_bf16(a, b, c, 0, 0, 0);
}

static __device__ inline bf16x8 load8_f32_to_bf16(const float* __restrict__ p) {
    f32x4 a = *(const f32x4*)p;
    f32x4 b = *(const f32x4*)(p + 4);
    bf16x8 o;
    o[0] = (__bf16)a[0]; o[1] = (__bf16)a[1]; o[2] = (__bf16)a[2]; o[3] = (__bf16)a[3];
    o[4] = (__bf16)b[0]; o[5] = (__bf16)b[1]; o[6] = (__bf16)b[2]; o[7] = (__bf16)b[3];
    return o;
}

static __device__ inline bf16x8 cvt2_bf16(f32x4 a, f32x4 b) {
    bf16x8 o;
    o[0] = (__bf16)a[0]; o[1] = (__bf16)a[1]; o[2] = (__bf16)a[2]; o[3] = (__bf16)a[3];
    o[4] = (__bf16)b[0]; o[5] = (__bf16)b[1]; o[6] = (__bf16)b[2]; o[7] = (__bf16)b[3];
    return o;
}

// ---------------------------------------------------------------------------
// Weight pre-pack: W [K, Ncols] fp32 row-major -> MFMA B-fragment order, bf16
// ---------------------------------------------------------------------------
__global__ void pack_kernel(const float* __restrict__ W, __bf16* __restrict__ out,
                            int K, int Ncols) {
    int idx = blockIdx.x * 256 + threadIdx.x;
    int total = (K >> 5) * (Ncols >> 4) * 64;
    if (idx >= total) return;
    int lane = idx & 63;
    int tc = idx >> 6;
    int nC = Ncols >> 4;
    int c = tc % nC;
    int t = tc / nC;
    int col = (c << 4) + (lane & 15);
    int k0 = (t << 5) + ((lane >> 4) << 3);
    bf16x8 v;
#pragma unroll
    for (int j = 0; j < 8; ++j) v[j] = (__bf16)W[(k0 + j) * Ncols + col];
    *((bf16x8*)out + idx) = v;
}

// ---------------------------------------------------------------------------
// CSR build
// ---------------------------------------------------------------------------
__global__ void hist_kernel(const int* __restrict__ eidx, int* __restrict__ counts) {
    int e = blockIdx.x * 256 + threadIdx.x;
    if (e < N_EDGES) {
        int r = eidx[N_EDGES + e];
        r = (r < 0) ? 0 : (r >= N_NODES ? N_NODES - 1 : r);
        atomicAdd(&counts[r], 1);
    }
}

__global__ __launch_bounds__(1024) void scan_kernel(const int* __restrict__ counts,
                                                    int* __restrict__ offsets,
                                                    int* __restrict__ cursor) {
    __shared__ int part[1024];
    const int t = threadIdx.x;
    const int CH = (N_NODES + 1023) / 1024;   // 49
    const int base = t * CH;
    int s = 0;
#pragma unroll 1
    for (int i = 0; i < CH; ++i) {
        int idx = base + i;
        if (idx < N_NODES) s += counts[idx];
    }
    part[t] = s;
    __syncthreads();
    for (int d = 1; d < 1024; d <<= 1) {
        int x = (t >= d) ? part[t - d] : 0;
        __syncthreads();
        part[t] += x;
        __syncthreads();
    }
    int run = part[t] - s;
#pragma unroll 1
    for (int i = 0; i < CH; ++i) {
        int idx = base + i;
        if (idx < N_NODES) {
            offsets[idx] = run;
            cursor[idx]  = run;
            run += counts[idx];
        }
    }
    if (t == 1023) offsets[N_NODES] = run;
}

__global__ void scatter_kernel(const int* __restrict__ eidx,
                               int* __restrict__ cursor, int* __restrict__ eids) {
    int e = blockIdx.x * 256 + threadIdx.x;
    if (e < N_EDGES) {
        int r = eidx[N_EDGES + e];
        r = (r < 0) ? 0 : (r >= N_NODES ? N_NODES - 1 : r);
        int pos = atomicAdd(&cursor[r], 1);
        eids[pos] = e;
    }
}

// ---------------------------------------------------------------------------
// Fused MLP core (as round 7): 32 rows, 4 waves, in-register LN, B-prefetch,
// XOR-swizzled h'. Leaves GEMM2 accum (row m*16+g*4+r, col 32w+16n+l16).
// NO trailing barrier — caller must sync before reusing lds.
// ---------------------------------------------------------------------------
template<int ASTRIDE, int T1>
__device__ inline void mlp_core(char* lds,
                                const bf16x8* __restrict__ pW1,
                                const bf16x8* __restrict__ pW2,
                                const float* __restrict__ b1,
                                const float* __restrict__ g1,
                                const float* __restrict__ be1,
                                f32x4 (&acc2)[2][2]) {
    const int tid = threadIdx.x;
    const int w = tid >> 6;
    const int lane = tid & 63;
    const int l16 = lane & 15;
    const int g = lane >> 4;
    float* stats = (float*)(lds + 32 * ASTRIDE);   // [32][8]: (sum,sq) x 4 waves

    // ---- GEMM1: [32,K1] x [K1,256], wave w owns cols [64w, 64w+64) ----
    f32x4 acc[2][4];
#pragma unroll
    for (int m = 0; m < 2; ++m)
#pragma unroll
        for (int n = 0; n < 4; ++n) acc[m][n] = (f32x4){0.f, 0.f, 0.f, 0.f};
    bf16x8 bc[4];
    {
        const bf16x8* bp = pW1 + ((4 * w) << 6) + lane;
#pragma unroll
        for (int n = 0; n < 4; ++n) bc[n] = bp[n << 6];
    }
#pragma unroll
    for (int t = 0; t < T1; ++t) {
        bf16x8 af0 = *(const bf16x8*)(lds + l16 * ASTRIDE + t * 64 + g * 16);
        bf16x8 af1 = *(const bf16x8*)(lds + (16 + l16) * ASTRIDE + t * 64 + g * 16);
        bf16x8 bn[4];
        if (t + 1 < T1) {
            const bf16x8* bp = pW1 + (((t + 1) * 16 + 4 * w) << 6) + lane;
#pragma unroll
            for (int n = 0; n < 4; ++n) bn[n] = bp[n << 6];
        }
#pragma unroll
        for (int n = 0; n < 4; ++n) {
            acc[0][n] = mfma16x16x32(af0, bc[n], acc[0][n]);
            acc[1][n] = mfma16x16x32(af1, bc[n], acc[1][n]);
        }
        if (t + 1 < T1) {
#pragma unroll
            for (int n = 0; n < 4; ++n) bc[n] = bn[n];
        }
    }

    // ---- bias + per-row stats (in-register, 16-lane reduce) ----
    float b1v[4];
#pragma unroll
    for (int n = 0; n < 4; ++n) b1v[n] = b1[64 * w + 16 * n + l16];
#pragma unroll
    for (int m = 0; m < 2; ++m)
#pragma unroll
        for (int r = 0; r < 4; ++r) {
            float s = 0.f, q = 0.f;
#pragma unroll
            for (int n = 0; n < 4; ++n) {
                float x = acc[m][n][r] + b1v[n];
                acc[m][n][r] = x;
                s += x; q += x * x;
            }
            s += __shfl_xor(s, 1); q += __shfl_xor(q, 1);
            s += __shfl_xor(s, 2); q += __shfl_xor(q, 2);
            s += __shfl_xor(s, 4); q += __shfl_xor(q, 4);
            s += __shfl_xor(s, 8); q += __shfl_xor(q, 8);
            if (l16 == 0) {
                int row = m * 16 + g * 4 + r;
                *(f32x2*)(stats + row * 8 + w * 2) = (f32x2){s, q};
            }
        }
    __syncthreads();   // GEMM1 A-reads done everywhere; stats visible

    // ---- finish LN stats; apply LN + SiLU; write h' (over A region, swz) ----
    float mu[2][4], rs[2][4];
#pragma unroll
    for (int m = 0; m < 2; ++m)
#pragma unroll
        for (int r = 0; r < 4; ++r) {
            int row = m * 16 + g * 4 + r;
            f32x4 a = *(const f32x4*)(stats + row * 8);
            f32x4 b = *(const f32x4*)(stats + row * 8 + 4);
            float S = (a[0] + a[2]) + (b[0] + b[2]);
            float Q = (a[1] + a[3]) + (b[1] + b[3]);
            float mm = S * (1.f / 256.f);
            float vv = fmaxf(Q * (1.f / 256.f) - mm * mm, 0.f);
            mu[m][r] = mm;
            rs[m][r] = rsqrtf(vv + 1e-5f);
        }
    float g1v[4], bev[4];
#pragma unroll
    for (int n = 0; n < 4; ++n) {
        g1v[n] = g1[64 * w + 16 * n + l16];
        bev[n] = be1[64 * w + 16 * n + l16];
    }
    const int wswz = g << 4;   // (row&12)<<2 with row = m*16+g*4+r, r<4
#pragma unroll
    for (int m = 0; m < 2; ++m)
#pragma unroll
        for (int n = 0; n < 4; ++n)
#pragma unroll
            for (int r = 0; r < 4; ++r) {
                float x = (acc[m][n][r] - mu[m][r]) * rs[m][r] * g1v[n] + bev[n];
                x = x / (1.f + __expf(-x));   // SiLU
                int row = m * 16 + g * 4 + r;
                int col = 64 * w + 16 * n + l16;
                *(__bf16*)(lds + ((row * 528 + col * 2) ^ wswz)) = (__bf16)x;
            }
    __syncthreads();   // h' complete

    // ---- GEMM2: [32,256] x [256,128], wave w owns cols [32w, 32w+32) ----
#pragma unroll
    for (int m = 0; m < 2; ++m)
#pragma unroll
        for (int n = 0; n < 2; ++n) acc2[m][n] = (f32x4){0.f, 0.f, 0.f, 0.f};
    const int rsw = (l16 & 12) << 2;
    bf16x8 c0, c1;
    {
        const bf16x8* bp = pW2 + ((2 * w) << 6) + lane;
        c0 = bp[0]; c1 = bp[1 << 6];
    }
#pragma unroll
    for (int t = 0; t < 8; ++t) {
        bf16x8 af0 = *(const bf16x8*)(lds + ((l16 * 528 + t * 64 + g * 16) ^ rsw));
        bf16x8 af1 = *(const bf16x8*)(lds + (((16 + l16) * 528 + t * 64 + g * 16) ^ rsw));
        bf16x8 n0, n1;
        if (t < 7) {
            const bf16x8* bp = pW2 + (((t + 1) * 8 + 2 * w) << 6) + lane;
            n0 = bp[0]; n1 = bp[1 << 6];
        }
        acc2[0][0] = mfma16x16x32(af0, c0, acc2[0][0]);
        acc2[1][0] = mfma16x16x32(af1, c0, acc2[1][0]);
        acc2[0][1] = mfma16x16x32(af0, c1, acc2[0][1]);
        acc2[1][1] = mfma16x16x32(af1, c1, acc2[1][1]);
        if (t < 7) { c0 = n0; c1 = n1; }
    }
}

// Scatter acc2+b2 into lds (f32, row stride 528B), then remap to staging
// ownership. Shared by both kernels (caller already synced after GEMM2).
static __device__ inline void acc2_to_lds(char* lds, f32x4 (&acc2)[2][2],
                                          const float* __restrict__ b2, int tid) {
    const int w = tid >> 6, lane = tid & 63;
    const int l16 = lane & 15, g = lane >> 4;
    float b2v[2];
#pragma unroll
    for (int n = 0; n < 2; ++n) b2v[n] = b2[32 * w + 16 * n + l16];
#pragma unroll
    for (int m = 0; m < 2; ++m)
#pragma unroll
        for (int n = 0; n < 2; ++n)
#pragma unroll
            for (int r = 0; r < 4; ++r) {
                int row = m * 16 + g * 4 + r;
                int col = 32 * w + 16 * n + l16;
                *(float*)(lds + row * 528 + (col << 2)) = acc2[m][n][r] + b2v[n];
            }
}

// ---------------------------------------------------------------------------
// Edge kernel: 32 edges/block, 5 blocks/CU; residual ef held in registers
// ---------------------------------------------------------------------------
__global__ __launch_bounds__(256, 5) void edge_kernel(
    const float* __restrict__ node, const float* __restrict__ ef,
    const int* __restrict__ eidx,
    const bf16x8* __restrict__ pW1, const bf16x8* __restrict__ pW2,
    const float* __restrict__ b1, const float* __restrict__ g1,
    const float* __restrict__ be1, const float* __restrict__ b2,
    float* __restrict__ out_edges) {
    __shared__ __align__(16) char lds[MR * 784 + MR * 32];   // 26112 B
    const int tid = threadIdx.x;
    const int eb = blockIdx.x * MR;
    const int row = tid >> 3, l8 = tid & 7;

    f32x4 efr0, efr1, efr2, efr3;   // residual: ef[e][8l8..+8) and [64+8l8..+8)
    {   // stage A = [node[snd] | node[rcv] | ef] (bf16)
        int e = eb + row;
        int snd = eidx[e], rcv = eidx[N_EDGES + e];
        snd = (snd < 0) ? 0 : (snd >= N_NODES ? N_NODES - 1 : snd);
        rcv = (rcv < 0) ? 0 : (rcv >= N_NODES ? N_NODES - 1 : rcv);
        const float* ps = node + (size_t)snd * DIM;
        const float* pr = node + (size_t)rcv * DIM;
        const float* pe = ef + (size_t)e * DIM;
#pragma unroll
        for (int i = 0; i < 4; ++i) {
            int c = l8 + (i << 3);
            const float* src = (c < 16) ? (ps + (c << 3)) : (pr + ((c - 16) << 3));
            *(bf16x8*)(lds + row * 784 + (c << 4)) = load8_f32_to_bf16(src);
        }
        const float* s0 = pe + (l8 << 3);
        efr0 = ((const f32x4*)s0)[0]; efr1 = ((const f32x4*)s0)[1];
        const float* s1 = pe + 64 + (l8 << 3);
        efr2 = ((const f32x4*)s1)[0]; efr3 = ((const f32x4*)s1)[1];
        *(bf16x8*)(lds + row * 784 + ((32 + l8) << 4)) = cvt2_bf16(efr0, efr1);
        *(bf16x8*)(lds + row * 784 + ((40 + l8) << 4)) = cvt2_bf16(efr2, efr3);
    }
    __syncthreads();

    f32x4 acc2[2][2];
    mlp_core<784, 12>(lds, pW1, pW2, b1, g1, be1, acc2);

    __syncthreads();                 // all GEMM2 h' reads done
    acc2_to_lds(lds, acc2, b2, tid);
    __syncthreads();                 // mlp output (f32) staged

    {   // remap + residual add + wide store
        int e = eb + row;
        const char* base = lds + row * 528;
        f32x4 o0 = *(const f32x4*)(base + (l8 << 5));
        f32x4 o1 = *(const f32x4*)(base + (l8 << 5) + 16);
        f32x4 o2 = *(const f32x4*)(base + 256 + (l8 << 5));
        f32x4 o3 = *(const f32x4*)(base + 256 + (l8 << 5) + 16);
        o0 += efr0; o1 += efr1; o2 += efr2; o3 += efr3;
        float* op = out_edges + (size_t)e * DIM + (l8 << 3);
        *(f32x4*)op = o0; *(f32x4*)(op + 4) = o1;
        *(f32x4*)(op + 64) = o2; *(f32x4*)(op + 68) = o3;
    }
}

// ---------------------------------------------------------------------------
// Node kernel: 32 nodes/block; CSR gather; residual node held in registers
// ---------------------------------------------------------------------------
__global__ __launch_bounds__(256, 5) void node_kernel(
    const float* __restrict__ node, const float* __restrict__ out_edges,
    const int* __restrict__ offsets, const int* __restrict__ eids,
    const bf16x8* __restrict__ pW1, const bf16x8* __restrict__ pW2,
    const float* __restrict__ b1, const float* __restrict__ g1,
    const float* __restrict__ be1, const float* __restrict__ b2,
    float* __restrict__ out_nodes) {
    __shared__ __align__(16) char lds[MR * 528 + MR * 32];   // 17920 B
    const int tid = threadIdx.x;
    const int nb = blockIdx.x * MR;
    const int row = tid >> 3, l8 = tid & 7;

    f32x4 nr0, nr1, nr2, nr3;   // residual: node[n][8l8..+8) and [64+8l8..+8)
    {   // stage node_input = [node[n] | csr aggregate] -> bf16
        int n = nb + row;
        int nc = (n > N_NODES - 1) ? N_NODES - 1 : n;
        const float* pn = node + (size_t)nc * DIM;
        const float* s0 = pn + (l8 << 3);
        nr0 = ((const f32x4*)s0)[0]; nr1 = ((const f32x4*)s0)[1];
        const float* s1 = pn + 64 + (l8 << 3);
        nr2 = ((const f32x4*)s1)[0]; nr3 = ((const f32x4*)s1)[1];
        *(bf16x8*)(lds + row * 528 + (l8 << 4)) = cvt2_bf16(nr0, nr1);
        *(bf16x8*)(lds + row * 528 + ((8 + l8) << 4)) = cvt2_bf16(nr2, nr3);
        // aggregate: lane owns 16 contiguous cols [l8*16, +16)
        float a[16];
#pragma unroll
        for (int j = 0; j < 16; ++j) a[j] = 0.f;
        int st = offsets[nc], en = offsets[nc + 1];
        int i = st;
#pragma unroll 1
        for (; i + 2 <= en; i += 2) {
            int e0 = eids[i], e1 = eids[i + 1];
            const float* er0 = out_edges + (size_t)e0 * DIM + (l8 << 4);
            const float* er1 = out_edges + (size_t)e1 * DIM + (l8 << 4);
            f32x4 u0 = ((const f32x4*)er0)[0], u1 = ((const f32x4*)er0)[1];
            f32x4 u2 = ((const f32x4*)er0)[2], u3 = ((const f32x4*)er0)[3];
            f32x4 v0 = ((const f32x4*)er1)[0], v1 = ((const f32x4*)er1)[1];
            f32x4 v2 = ((const f32x4*)er1)[2], v3 = ((const f32x4*)er1)[3];
#pragma unroll
            for (int k = 0; k < 4; ++k) {
                a[0 + k] += u0[k] + v0[k];
                a[4 + k] += u1[k] + v1[k];
                a[8 + k] += u2[k] + v2[k];
                a[12 + k] += u3[k] + v3[k];
            }
        }
        if (i < en) {
            int e0 = eids[i];
            const float* er0 = out_edges + (size_t)e0 * DIM + (l8 << 4);
#pragma unroll
            for (int k = 0; k < 4; ++k) {
                f32x4 v = ((const f32x4*)er0)[k];
                a[k * 4 + 0] += v[0]; a[k * 4 + 1] += v[1];
                a[k * 4 + 2] += v[2]; a[k * 4 + 3] += v[3];
            }
        }
        bf16x8 o0, o1;
#pragma unroll
        for (int j = 0; j < 8; ++j) { o0[j] = (__bf16)a[j]; o1[j] = (__bf16)a[8 + j]; }
        int cbase = 16 + (l8 << 1);
        *(bf16x8*)(lds + row * 528 + (cbase << 4)) = o0;
        *(bf16x8*)(lds + row * 528 + ((cbase + 1) << 4)) = o1;
    }
    __syncthreads();

    f32x4 acc2[2][2];
    mlp_core<528, 8>(lds, pW1, pW2, b1, g1, be1, acc2);

    __syncthreads();
    acc2_to_lds(lds, acc2, b2, tid);
    __syncthreads();

    {   // remap + residual add + wide store (guarded)
        int n = nb + row;
        if (n < N_NODES) {
            const char* base = lds + row * 528;
            f32x4 o0 = *(const f32x4*)(base + (l8 << 5));
            f32x4 o1 = *(const f32x4*)(base + (l8 << 5) + 16);
            f32x4 o2 = *(const f32x4*)(base + 256 + (l8 << 5));
            f32x4 o3 = *(const f32x4*)(base + 256 + (l8 << 5) + 16);
            o0 += nr0; o1 += nr1; o2 += nr2; o3 += nr3;
            float* op = out_nodes + (size_t)n * DIM + (l8 << 3);
            *(f32x4*)op = o0; *(f32x4*)(op + 4) = o1;
            *(f32x4*)(op + 64) = o2; *(f32x4*)(op + 68) = o3;
        }
    }
}

// ---------------------------------------------------------------------------
extern "C" void kernel_launch(void* const* d_in, const int* in_sizes, int n_in,
                              void* d_out, int out_size, void* d_ws, size_t ws_size,
                              hipStream_t stream) {
    const float* node  = (const float*)d_in[0];
    const float* ef    = (const float*)d_in[1];
    const int*   eidx  = (const int*)d_in[2];
    const float* eW1   = (const float*)d_in[3];
    const float* eb1   = (const float*)d_in[4];
    const float* eg1   = (const float*)d_in[5];
    const float* ebt1  = (const float*)d_in[6];
    const float* eW2   = (const float*)d_in[7];
    const float* eb2   = (const float*)d_in[8];
    const float* nW1   = (const float*)d_in[9];
    const float* nb1   = (const float*)d_in[10];
    const float* ng1   = (const float*)d_in[11];
    const float* nbt1  = (const float*)d_in[12];
    const float* nW2   = (const float*)d_in[13];
    const float* nb2   = (const float*)d_in[14];

    char* ws = (char*)d_ws;
    int* counts  = (int*)ws;
    int* offsets = counts + 50016;
    int* cursor  = offsets + 50016;
    int* eids    = cursor + 50016;
    char* wbase = (char*)(eids + 600064);
    __bf16* peW1 = (__bf16*)(((uintptr_t)wbase + 255) & ~(uintptr_t)255);
    __bf16* peW2 = peW1 + 384 * 256;
    __bf16* pnW1 = peW2 + 256 * 128;
    __bf16* pnW2 = pnW1 + 256 * 256;

    hipMemsetAsync(counts, 0, 50000 * sizeof(int), stream);
    pack_kernel<<<48, 256, 0, stream>>>(eW1, peW1, 384, 256);
    pack_kernel<<<16, 256, 0, stream>>>(eW2, peW2, 256, 128);
    pack_kernel<<<32, 256, 0, stream>>>(nW1, pnW1, 256, 256);
    pack_kernel<<<16, 256, 0, stream>>>(nW2, pnW2, 256, 128);

    hist_kernel<<<(N_EDGES + 255) / 256, 256, 0, stream>>>(eidx, counts);
    scan_kernel<<<1, 1024, 0, stream>>>(counts, offsets, cursor);
    scatter_kernel<<<(N_EDGES + 255) / 256, 256, 0, stream>>>(eidx, cursor, eids);

    float* out_nodes = (float*)d_out;
    float* out_edges = out_nodes + (size_t)N_NODES * DIM;

    edge_kernel<<<N_EDGES / MR, 256, 0, stream>>>(
        node, ef, eidx, (const bf16x8*)peW1, (const bf16x8*)peW2,
        eb1, eg1, ebt1, eb2, out_edges);
    node_kernel<<<(N_NODES + MR - 1) / MR, 256, 0, stream>>>(
        node, out_edges, offsets, eids, (const bf16x8*)pnW1, (const bf16x8*)pnW2,
        nb1, ng1, nbt1, nb2, out_nodes);
}

// Round 9
// 682.445 us; speedup vs baseline: 1.0530x; 1.0530x over previous
//
#include <hip/hip_runtime.h>

#define N_NODES 50000
#define N_EDGES 600000
#define DIM 128
#define HID 256
#define MR 32            // rows (edges/nodes) per block

typedef float  f32x4  __attribute__((ext_vector_type(4), aligned(16), may_alias));
typedef float  f32x2  __attribute__((ext_vector_type(2), aligned(8),  may_alias));
typedef __bf16 bf16x8 __attribute__((ext_vector_type(8), aligned(16), may_alias));
typedef int    i32x4  __attribute__((ext_vector_type(4), aligned(16), may_alias));

static __device__ inline f32x4 mfma16x16x32(bf16x8 a, bf16x8 b, f32x4 c) {
    return __builtin_amdgcn_mfma_f32_16x16x32_bf16(a, b, c, 0, 0, 0);
}

static __device__ inline bf16x8 cvt2_bf16(f32x4 a, f32x4 b) {
    bf16x8 o;
    o[0] = (__bf16)a[0]; o[1] = (__bf16)a[1]; o[2] = (__bf16)a[2]; o[3] = (__bf16)a[3];
    o[4] = (__bf16)b[0]; o[5] = (__bf16)b[1]; o[6] = (__bf16)b[2]; o[7] = (__bf16)b[3];
    return o;
}

// ---------------------------------------------------------------------------
// node features fp32 -> bf16 table (one-time, 12.8 MB)
// ---------------------------------------------------------------------------
__global__ void nbf_kernel(const float* __restrict__ node, __bf16* __restrict__ nbf) {
    int idx = blockIdx.x * 256 + threadIdx.x;     // 50000*16 chunks
    if (idx >= N_NODES * 16) return;
    int row = idx >> 4, c = idx & 15;
    const float* p = node + (size_t)row * DIM + (c << 3);
    f32x4 a = ((const f32x4*)p)[0], b = ((const f32x4*)p)[1];
    *(bf16x8*)(nbf + (size_t)row * DIM + (c << 3)) = cvt2_bf16(a, b);
}

// ---------------------------------------------------------------------------
// Weight pre-pack (all four weights in one launch):
// packed[((t*nC + c)*64 + lane)] = { W[t*32 + (lane>>4)*8 + j][c*16 + (lane&15)] }
// ---------------------------------------------------------------------------
static __device__ inline void pack_one(const float* __restrict__ W,
                                       __bf16* __restrict__ out,
                                       int idx, int Ncols) {
    int lane = idx & 63;
    int tc = idx >> 6;
    int nC = Ncols >> 4;
    int c = tc % nC;
    int t = tc / nC;
    int col = (c << 4) + (lane & 15);
    int k0 = (t << 5) + ((lane >> 4) << 3);
    bf16x8 v;
#pragma unroll
    for (int j = 0; j < 8; ++j) v[j] = (__bf16)W[(k0 + j) * Ncols + col];
    *((bf16x8*)out + idx) = v;
}

__global__ void pack_all_kernel(const float* __restrict__ eW1, const float* __restrict__ eW2,
                                const float* __restrict__ nW1, const float* __restrict__ nW2,
                                __bf16* __restrict__ peW1, __bf16* __restrict__ peW2,
                                __bf16* __restrict__ pnW1, __bf16* __restrict__ pnW2) {
    int idx = blockIdx.x * 256 + threadIdx.x;     // 28672 total
    if (idx < 12288)       pack_one(eW1, peW1, idx, 256);
    else if (idx < 16384)  pack_one(eW2, peW2, idx - 12288, 128);
    else if (idx < 24576)  pack_one(nW1, pnW1, idx - 16384, 256);
    else                   pack_one(nW2, pnW2, idx - 24576, 128);
}

// ---------------------------------------------------------------------------
// CSR build
// ---------------------------------------------------------------------------
__global__ void hist_kernel(const int* __restrict__ eidx, int* __restrict__ counts) {
    int e = blockIdx.x * 256 + threadIdx.x;
    if (e < N_EDGES) {
        int r = eidx[N_EDGES + e];
        r = (r < 0) ? 0 : (r >= N_NODES ? N_NODES - 1 : r);
        atomicAdd(&counts[r], 1);
    }
}

__global__ __launch_bounds__(1024) void scan_kernel(const int* __restrict__ counts,
                                                    int* __restrict__ offsets,
                                                    int* __restrict__ cursor) {
    __shared__ int part[1024];
    const int t = threadIdx.x;
    const int CH = (N_NODES + 1023) / 1024;   // 49
    const int base = t * CH;
    int s = 0;
#pragma unroll 1
    for (int i = 0; i < CH; ++i) {
        int idx = base + i;
        if (idx < N_NODES) s += counts[idx];
    }
    part[t] = s;
    __syncthreads();
    for (int d = 1; d < 1024; d <<= 1) {
        int x = (t >= d) ? part[t - d] : 0;
        __syncthreads();
        part[t] += x;
        __syncthreads();
    }
    int run = part[t] - s;
#pragma unroll 1
    for (int i = 0; i < CH; ++i) {
        int idx = base + i;
        if (idx < N_NODES) {
            offsets[idx] = run;
            cursor[idx]  = run;
            run += counts[idx];
        }
    }
    if (t == 1023) offsets[N_NODES] = run;
}

__global__ void scatter_kernel(const int* __restrict__ eidx,
                               int* __restrict__ cursor, int* __restrict__ eids) {
    int e = blockIdx.x * 256 + threadIdx.x;
    if (e < N_EDGES) {
        int r = eidx[N_EDGES + e];
        r = (r < 0) ? 0 : (r >= N_NODES ? N_NODES - 1 : r);
        int pos = atomicAdd(&cursor[r], 1);
        eids[pos] = e;
    }
}

// ---------------------------------------------------------------------------
// Fused MLP core — EXACT round-6 structure (no swizzle, no source prefetch).
// 32 rows, 4 waves (4-way N-split), in-register LayerNorm.
// ---------------------------------------------------------------------------
template<int ASTRIDE, int T1>
__device__ inline void mlp_core(char* lds,
                                const bf16x8* __restrict__ pW1,
                                const bf16x8* __restrict__ pW2,
                                const float* __restrict__ b1,
                                const float* __restrict__ g1,
                                const float* __restrict__ be1,
                                f32x4 (&acc2)[2][2]) {
    const int tid = threadIdx.x;
    const int w = tid >> 6;
    const int lane = tid & 63;
    const int l16 = lane & 15;
    const int g = lane >> 4;
    float* stats = (float*)(lds + 32 * ASTRIDE);   // [32][8]: (sum,sq) x 4 waves

    // ---- GEMM1: [32,K1] x [K1,256], wave w owns cols [64w, 64w+64) ----
    f32x4 acc[2][4];
#pragma unroll
    for (int m = 0; m < 2; ++m)
#pragma unroll
        for (int n = 0; n < 4; ++n) acc[m][n] = (f32x4){0.f, 0.f, 0.f, 0.f};
#pragma unroll
    for (int t = 0; t < T1; ++t) {
        bf16x8 af[2];
#pragma unroll
        for (int m = 0; m < 2; ++m)
            af[m] = *(const bf16x8*)(lds + (m * 16 + l16) * ASTRIDE + t * 64 + g * 16);
        const bf16x8* bp = pW1 + ((t * 16 + 4 * w) << 6) + lane;
#pragma unroll
        for (int n = 0; n < 4; ++n) {
            bf16x8 bf = bp[n << 6];
#pragma unroll
            for (int m = 0; m < 2; ++m)
                acc[m][n] = mfma16x16x32(af[m], bf, acc[m][n]);
        }
    }

    // ---- bias + per-row stats (in-register, 16-lane reduce) ----
    float b1v[4];
#pragma unroll
    for (int n = 0; n < 4; ++n) b1v[n] = b1[64 * w + 16 * n + l16];
#pragma unroll
    for (int m = 0; m < 2; ++m)
#pragma unroll
        for (int r = 0; r < 4; ++r) {
            float s = 0.f, q = 0.f;
#pragma unroll
            for (int n = 0; n < 4; ++n) {
                float x = acc[m][n][r] + b1v[n];
                acc[m][n][r] = x;
                s += x; q += x * x;
            }
            s += __shfl_xor(s, 1); q += __shfl_xor(q, 1);
            s += __shfl_xor(s, 2); q += __shfl_xor(q, 2);
            s += __shfl_xor(s, 4); q += __shfl_xor(q, 4);
            s += __shfl_xor(s, 8); q += __shfl_xor(q, 8);
            if (l16 == 0) {
                int row = m * 16 + g * 4 + r;
                *(f32x2*)(stats + row * 8 + w * 2) = (f32x2){s, q};
            }
        }
    __syncthreads();   // GEMM1 A-reads done everywhere; stats visible

    // ---- finish LN stats; apply LN + SiLU; write h' (over A region) ----
    float mu[2][4], rs[2][4];
#pragma unroll
    for (int m = 0; m < 2; ++m)
#pragma unroll
        for (int r = 0; r < 4; ++r) {
            int row = m * 16 + g * 4 + r;
            f32x4 a = *(const f32x4*)(stats + row * 8);
            f32x4 b = *(const f32x4*)(stats + row * 8 + 4);
            float S = (a[0] + a[2]) + (b[0] + b[2]);
            float Q = (a[1] + a[3]) + (b[1] + b[3]);
            float mm = S * (1.f / 256.f);
            float vv = fmaxf(Q * (1.f / 256.f) - mm * mm, 0.f);
            mu[m][r] = mm;
            rs[m][r] = rsqrtf(vv + 1e-5f);
        }
    float g1v[4], bev[4];
#pragma unroll
    for (int n = 0; n < 4; ++n) {
        g1v[n] = g1[64 * w + 16 * n + l16];
        bev[n] = be1[64 * w + 16 * n + l16];
    }
#pragma unroll
    for (int m = 0; m < 2; ++m)
#pragma unroll
        for (int n = 0; n < 4; ++n)
#pragma unroll
            for (int r = 0; r < 4; ++r) {
                float x = (acc[m][n][r] - mu[m][r]) * rs[m][r] * g1v[n] + bev[n];
                x = x / (1.f + __expf(-x));   // SiLU
                int row = m * 16 + g * 4 + r;
                int col = 64 * w + 16 * n + l16;
                *(__bf16*)(lds + row * 528 + col * 2) = (__bf16)x;
            }
    __syncthreads();   // h' complete

    // ---- GEMM2: [32,256] x [256,128], wave w owns cols [32w, 32w+32) ----
#pragma unroll
    for (int m = 0; m < 2; ++m)
#pragma unroll
        for (int n = 0; n < 2; ++n) acc2[m][n] = (f32x4){0.f, 0.f, 0.f, 0.f};
#pragma unroll
    for (int t = 0; t < 8; ++t) {
        bf16x8 af[2];
#pragma unroll
        for (int m = 0; m < 2; ++m)
            af[m] = *(const bf16x8*)(lds + (m * 16 + l16) * 528 + t * 64 + g * 16);
        const bf16x8* bp = pW2 + ((t * 8 + 2 * w) << 6) + lane;
#pragma unroll
        for (int n = 0; n < 2; ++n) {
            bf16x8 bf = bp[n << 6];
#pragma unroll
            for (int m = 0; m < 2; ++m)
                acc2[m][n] = mfma16x16x32(af[m], bf, acc2[m][n]);
        }
    }
}

// ---------------------------------------------------------------------------
// Edge kernel: 32 edges/block, 6 blocks/CU target; bf16 node-table gathers
// ---------------------------------------------------------------------------
__global__ __launch_bounds__(256, 6) void edge_kernel(
    const __bf16* __restrict__ nbf, const float* __restrict__ ef,
    const int* __restrict__ eidx,
    const bf16x8* __restrict__ pW1, const bf16x8* __restrict__ pW2,
    const float* __restrict__ b1, const float* __restrict__ g1,
    const float* __restrict__ be1, const float* __restrict__ b2,
    float* __restrict__ out_edges) {
    __shared__ __align__(16) char lds[MR * 784 + MR * 32];   // 26112 B
    const int tid = threadIdx.x;
    const int eb = blockIdx.x * MR;

    {   // stage A = [nbf[snd] | nbf[rcv] | cvt(ef)] : per thread 32B snd + 32B rcv + 16 ef cols
        int row = tid >> 3, l8 = tid & 7;
        int e = eb + row;
        int snd = eidx[e], rcv = eidx[N_EDGES + e];
        snd = (snd < 0) ? 0 : (snd >= N_NODES ? N_NODES - 1 : snd);
        rcv = (rcv < 0) ? 0 : (rcv >= N_NODES ? N_NODES - 1 : rcv);
        const char* ps = (const char*)(nbf + (size_t)snd * DIM) + (l8 << 5);
        const char* pr = (const char*)(nbf + (size_t)rcv * DIM) + (l8 << 5);
        char* dst = lds + row * 784 + (l8 << 5);
        *(i32x4*)dst         = *(const i32x4*)ps;
        *(i32x4*)(dst + 16)  = *(const i32x4*)(ps + 16);
        *(i32x4*)(dst + 256) = *(const i32x4*)pr;
        *(i32x4*)(dst + 272) = *(const i32x4*)(pr + 16);
        const float* pe = ef + (size_t)e * DIM + (l8 << 4);
        f32x4 a0 = ((const f32x4*)pe)[0], a1 = ((const f32x4*)pe)[1];
        f32x4 a2 = ((const f32x4*)pe)[2], a3 = ((const f32x4*)pe)[3];
        *(bf16x8*)(dst + 512) = cvt2_bf16(a0, a1);
        *(bf16x8*)(dst + 528) = cvt2_bf16(a2, a3);
    }
    __syncthreads();

    f32x4 acc2[2][2];
    mlp_core<784, 12>(lds, pW1, pW2, b1, g1, be1, acc2);

    {   // epilogue: out = ef + (h' @ W2 + b2), direct from registers (round-6 pattern)
        const int w = tid >> 6, lane = tid & 63;
        const int l16 = lane & 15, g = lane >> 4;
        float b2v[2];
#pragma unroll
        for (int n = 0; n < 2; ++n) b2v[n] = b2[32 * w + 16 * n + l16];
#pragma unroll
        for (int m = 0; m < 2; ++m)
#pragma unroll
            for (int n = 0; n < 2; ++n)
#pragma unroll
                for (int r = 0; r < 4; ++r) {
                    int e = eb + m * 16 + g * 4 + r;
                    int col = 32 * w + 16 * n + l16;
                    size_t off = (size_t)e * DIM + col;
                    out_edges[off] = acc2[m][n][r] + b2v[n] + ef[off];
                }
    }
}

// ---------------------------------------------------------------------------
// Node kernel: 32 nodes/block; bf16 node staging; CSR gather unrolled x2
// ---------------------------------------------------------------------------
__global__ __launch_bounds__(256, 6) void node_kernel(
    const float* __restrict__ node, const __bf16* __restrict__ nbf,
    const float* __restrict__ out_edges,
    const int* __restrict__ offsets, const int* __restrict__ eids,
    const bf16x8* __restrict__ pW1, const bf16x8* __restrict__ pW2,
    const float* __restrict__ b1, const float* __restrict__ g1,
    const float* __restrict__ be1, const float* __restrict__ b2,
    float* __restrict__ out_nodes) {
    __shared__ __align__(16) char lds[MR * 528 + MR * 32];   // 17920 B
    const int tid = threadIdx.x;
    const int nb = blockIdx.x * MR;

    {   // stage node_input = [nbf[n] | csr aggregate] -> bf16
        int row = tid >> 3, l8 = tid & 7;
        int n = nb + row;
        int nc = (n > N_NODES - 1) ? N_NODES - 1 : n;
        const char* pn = (const char*)(nbf + (size_t)nc * DIM) + (l8 << 5);
        char* dst = lds + row * 528 + (l8 << 5);
        *(i32x4*)dst        = *(const i32x4*)pn;
        *(i32x4*)(dst + 16) = *(const i32x4*)(pn + 16);
        // aggregate: lane owns 16 contiguous cols [l8*16, +16)
        float a[16];
#pragma unroll
        for (int j = 0; j < 16; ++j) a[j] = 0.f;
        int st = offsets[nc], en = offsets[nc + 1];
        int i = st;
#pragma unroll 1
        for (; i + 2 <= en; i += 2) {
            int e0 = eids[i], e1 = eids[i + 1];
            const float* er0 = out_edges + (size_t)e0 * DIM + (l8 << 4);
            const float* er1 = out_edges + (size_t)e1 * DIM + (l8 << 4);
            f32x4 u0 = ((const f32x4*)er0)[0], u1 = ((const f32x4*)er0)[1];
            f32x4 u2 = ((const f32x4*)er0)[2], u3 = ((const f32x4*)er0)[3];
            f32x4 v0 = ((const f32x4*)er1)[0], v1 = ((const f32x4*)er1)[1];
            f32x4 v2 = ((const f32x4*)er1)[2], v3 = ((const f32x4*)er1)[3];
#pragma unroll
            for (int k = 0; k < 4; ++k) {
                a[0 + k]  += u0[k] + v0[k];
                a[4 + k]  += u1[k] + v1[k];
                a[8 + k]  += u2[k] + v2[k];
                a[12 + k] += u3[k] + v3[k];
            }
        }
        if (i < en) {
            int e0 = eids[i];
            const float* er0 = out_edges + (size_t)e0 * DIM + (l8 << 4);
#pragma unroll
            for (int k = 0; k < 4; ++k) {
                f32x4 v = ((const f32x4*)er0)[k];
                a[k * 4 + 0] += v[0]; a[k * 4 + 1] += v[1];
                a[k * 4 + 2] += v[2]; a[k * 4 + 3] += v[3];
            }
        }
        bf16x8 o0, o1;
#pragma unroll
        for (int j = 0; j < 8; ++j) { o0[j] = (__bf16)a[j]; o1[j] = (__bf16)a[8 + j]; }
        int cbase = 16 + (l8 << 1);
        *(bf16x8*)(lds + row * 528 + (cbase << 4)) = o0;
        *(bf16x8*)(lds + row * 528 + ((cbase + 1) << 4)) = o1;
    }
    __syncthreads();

    f32x4 acc2[2][2];
    mlp_core<528, 8>(lds, pW1, pW2, b1, g1, be1, acc2);

    {   // epilogue: out = node + (h' @ W2 + b2), guarded (round-6 pattern)
        const int w = tid >> 6, lane = tid & 63;
        const int l16 = lane & 15, g = lane >> 4;
        float b2v[2];
#pragma unroll
        for (int n = 0; n < 2; ++n) b2v[n] = b2[32 * w + 16 * n + l16];
#pragma unroll
        for (int m = 0; m < 2; ++m)
#pragma unroll
            for (int n = 0; n < 2; ++n)
#pragma unroll
                for (int r = 0; r < 4; ++r) {
                    int nd = nb + m * 16 + g * 4 + r;
                    if (nd < N_NODES) {
                        int col = 32 * w + 16 * n + l16;
                        size_t off = (size_t)nd * DIM + col;
                        out_nodes[off] = acc2[m][n][r] + b2v[n] + node[off];
                    }
                }
    }
}

// ---------------------------------------------------------------------------
extern "C" void kernel_launch(void* const* d_in, const int* in_sizes, int n_in,
                              void* d_out, int out_size, void* d_ws, size_t ws_size,
                              hipStream_t stream) {
    const float* node  = (const float*)d_in[0];
    const float* ef    = (const float*)d_in[1];
    const int*   eidx  = (const int*)d_in[2];
    const float* eW1   = (const float*)d_in[3];
    const float* eb1   = (const float*)d_in[4];
    const float* eg1   = (const float*)d_in[5];
    const float* ebt1  = (const float*)d_in[6];
    const float* eW2   = (const float*)d_in[7];
    const float* eb2   = (const float*)d_in[8];
    const float* nW1   = (const float*)d_in[9];
    const float* nb1   = (const float*)d_in[10];
    const float* ng1   = (const float*)d_in[11];
    const float* nbt1  = (const float*)d_in[12];
    const float* nW2   = (const float*)d_in[13];
    const float* nb2   = (const float*)d_in[14];

    char* ws = (char*)d_ws;
    int* counts  = (int*)ws;
    int* offsets = counts + 50016;
    int* cursor  = offsets + 50016;
    int* eids    = cursor + 50016;
    char* nbase = (char*)(eids + 600064);
    __bf16* nbf = (__bf16*)(((uintptr_t)nbase + 255) & ~(uintptr_t)255);   // 12.8 MB
    __bf16* peW1 = nbf + (size_t)N_NODES * DIM;
    __bf16* peW2 = peW1 + 384 * 256;
    __bf16* pnW1 = peW2 + 256 * 128;
    __bf16* pnW2 = pnW1 + 256 * 256;

    hipMemsetAsync(counts, 0, 50000 * sizeof(int), stream);
    nbf_kernel<<<(N_NODES * 16 + 255) / 256, 256, 0, stream>>>(node, nbf);
    pack_all_kernel<<<112, 256, 0, stream>>>(eW1, eW2, nW1, nW2, peW1, peW2, pnW1, pnW2);

    hist_kernel<<<(N_EDGES + 255) / 256, 256, 0, stream>>>(eidx, counts);
    scan_kernel<<<1, 1024, 0, stream>>>(counts, offsets, cursor);
    scatter_kernel<<<(N_EDGES + 255) / 256, 256, 0, stream>>>(eidx, cursor, eids);

    float* out_nodes = (float*)d_out;
    float* out_edges = out_nodes + (size_t)N_NODES * DIM;

    edge_kernel<<<N_EDGES / MR, 256, 0, stream>>>(
        nbf, ef, eidx, (const bf16x8*)peW1, (const bf16x8*)peW2,
        eb1, eg1, ebt1, eb2, out_edges);
    node_kernel<<<(N_NODES + MR - 1) / MR, 256, 0, stream>>>(
        node, nbf, out_edges, offsets, eids, (const bf16x8*)pnW1, (const bf16x8*)pnW2,
        nb1, ng1, nbt1, nb2, out_nodes);
}

// Round 10
// 619.743 us; speedup vs baseline: 1.1595x; 1.1012x over previous
//
#include <hip/hip_runtime.h>

#define N_NODES 50000
#define N_EDGES 600000
#define DIM 128
#define HID 256
#define MR 32            // rows (edges/nodes) per block

typedef float  f32x4  __attribute__((ext_vector_type(4), aligned(16), may_alias));
typedef float  f32x2  __attribute__((ext_vector_type(2), aligned(8),  may_alias));
typedef __bf16 bf16x8 __attribute__((ext_vector_type(8), aligned(16), may_alias));
typedef int    i32x4  __attribute__((ext_vector_type(4), aligned(16), may_alias));

static __device__ inline f32x4 mfma16x16x32(bf16x8 a, bf16x8 b, f32x4 c) {
    return __builtin_amdgcn_mfma_f32_16x16x32_bf16(a, b, c, 0, 0, 0);
}

static __device__ inline bf16x8 cvt2_bf16(f32x4 a, f32x4 b) {
    bf16x8 o;
    o[0] = (__bf16)a[0]; o[1] = (__bf16)a[1]; o[2] = (__bf16)a[2]; o[3] = (__bf16)a[3];
    o[4] = (__bf16)b[0]; o[5] = (__bf16)b[1]; o[6] = (__bf16)b[2]; o[7] = (__bf16)b[3];
    return o;
}

// ---------------------------------------------------------------------------
// node features fp32 -> bf16 table (one-time, 12.8 MB)
// ---------------------------------------------------------------------------
__global__ void nbf_kernel(const float* __restrict__ node, __bf16* __restrict__ nbf) {
    int idx = blockIdx.x * 256 + threadIdx.x;     // 50000*16 chunks
    if (idx >= N_NODES * 16) return;
    int row = idx >> 4, c = idx & 15;
    const float* p = node + (size_t)row * DIM + (c << 3);
    f32x4 a = ((const f32x4*)p)[0], b = ((const f32x4*)p)[1];
    *(bf16x8*)(nbf + (size_t)row * DIM + (c << 3)) = cvt2_bf16(a, b);
}

// ---------------------------------------------------------------------------
// Weight pre-pack (all four weights in one launch)
// ---------------------------------------------------------------------------
static __device__ inline void pack_one(const float* __restrict__ W,
                                       __bf16* __restrict__ out,
                                       int idx, int Ncols) {
    int lane = idx & 63;
    int tc = idx >> 6;
    int nC = Ncols >> 4;
    int c = tc % nC;
    int t = tc / nC;
    int col = (c << 4) + (lane & 15);
    int k0 = (t << 5) + ((lane >> 4) << 3);
    bf16x8 v;
#pragma unroll
    for (int j = 0; j < 8; ++j) v[j] = (__bf16)W[(k0 + j) * Ncols + col];
    *((bf16x8*)out + idx) = v;
}

__global__ void pack_all_kernel(const float* __restrict__ eW1, const float* __restrict__ eW2,
                                const float* __restrict__ nW1, const float* __restrict__ nW2,
                                __bf16* __restrict__ peW1, __bf16* __restrict__ peW2,
                                __bf16* __restrict__ pnW1, __bf16* __restrict__ pnW2) {
    int idx = blockIdx.x * 256 + threadIdx.x;     // 28672 total
    if (idx < 12288)       pack_one(eW1, peW1, idx, 256);
    else if (idx < 16384)  pack_one(eW2, peW2, idx - 12288, 128);
    else if (idx < 24576)  pack_one(nW1, pnW1, idx - 16384, 256);
    else                   pack_one(nW2, pnW2, idx - 24576, 128);
}

// ---------------------------------------------------------------------------
// CSR build
// ---------------------------------------------------------------------------
__global__ void hist_kernel(const int* __restrict__ eidx, int* __restrict__ counts) {
    int e = blockIdx.x * 256 + threadIdx.x;
    if (e < N_EDGES) {
        int r = eidx[N_EDGES + e];
        r = (r < 0) ? 0 : (r >= N_NODES ? N_NODES - 1 : r);
        atomicAdd(&counts[r], 1);
    }
}

__global__ __launch_bounds__(1024) void scan_kernel(const int* __restrict__ counts,
                                                    int* __restrict__ offsets,
                                                    int* __restrict__ cursor) {
    __shared__ int part[1024];
    const int t = threadIdx.x;
    const int CH = (N_NODES + 1023) / 1024;   // 49
    const int base = t * CH;
    int s = 0;
#pragma unroll 1
    for (int i = 0; i < CH; ++i) {
        int idx = base + i;
        if (idx < N_NODES) s += counts[idx];
    }
    part[t] = s;
    __syncthreads();
    for (int d = 1; d < 1024; d <<= 1) {
        int x = (t >= d) ? part[t - d] : 0;
        __syncthreads();
        part[t] += x;
        __syncthreads();
    }
    int run = part[t] - s;
#pragma unroll 1
    for (int i = 0; i < CH; ++i) {
        int idx = base + i;
        if (idx < N_NODES) {
            offsets[idx] = run;
            cursor[idx]  = run;
            run += counts[idx];
        }
    }
    if (t == 1023) offsets[N_NODES] = run;
}

__global__ void scatter_kernel(const int* __restrict__ eidx,
                               int* __restrict__ cursor, int* __restrict__ eids) {
    int e = blockIdx.x * 256 + threadIdx.x;
    if (e < N_EDGES) {
        int r = eidx[N_EDGES + e];
        r = (r < 0) ? 0 : (r >= N_NODES ? N_NODES - 1 : r);
        int pos = atomicAdd(&cursor[r], 1);
        eids[pos] = e;
    }
}

// ---------------------------------------------------------------------------
// Fused MLP core: round-6 GEMM structure + vectorized stats/LN and
// fast-math SiLU (exp2 + rcp instead of expf + IEEE div).
// ---------------------------------------------------------------------------
template<int ASTRIDE, int T1>
__device__ inline void mlp_core(char* lds,
                                const bf16x8* __restrict__ pW1,
                                const bf16x8* __restrict__ pW2,
                                const float* __restrict__ b1,
                                const float* __restrict__ g1,
                                const float* __restrict__ be1,
                                f32x4 (&acc2)[2][2]) {
    const int tid = threadIdx.x;
    const int w = tid >> 6;
    const int lane = tid & 63;
    const int l16 = lane & 15;
    const int g = lane >> 4;
    float* stats = (float*)(lds + 32 * ASTRIDE);   // [32][8]: (sum,sq) x 4 waves

    // ---- GEMM1: [32,K1] x [K1,256], wave w owns cols [64w, 64w+64) ----
    f32x4 acc[2][4];
#pragma unroll
    for (int m = 0; m < 2; ++m)
#pragma unroll
        for (int n = 0; n < 4; ++n) acc[m][n] = (f32x4){0.f, 0.f, 0.f, 0.f};
#pragma unroll
    for (int t = 0; t < T1; ++t) {
        bf16x8 af[2];
#pragma unroll
        for (int m = 0; m < 2; ++m)
            af[m] = *(const bf16x8*)(lds + (m * 16 + l16) * ASTRIDE + t * 64 + g * 16);
        const bf16x8* bp = pW1 + ((t * 16 + 4 * w) << 6) + lane;
#pragma unroll
        for (int n = 0; n < 4; ++n) {
            bf16x8 bf = bp[n << 6];
#pragma unroll
            for (int m = 0; m < 2; ++m)
                acc[m][n] = mfma16x16x32(af[m], bf, acc[m][n]);
        }
    }

    // ---- bias + per-row stats (vectorized over r; packed-f32 eligible) ----
    float b1v[4];
#pragma unroll
    for (int n = 0; n < 4; ++n) b1v[n] = b1[64 * w + 16 * n + l16];
#pragma unroll
    for (int m = 0; m < 2; ++m) {
#pragma unroll
        for (int n = 0; n < 4; ++n) acc[m][n] += b1v[n];
        f32x4 s = (acc[m][0] + acc[m][1]) + (acc[m][2] + acc[m][3]);
        f32x4 q = acc[m][0] * acc[m][0];
        q = acc[m][1] * acc[m][1] + q;
        q = acc[m][2] * acc[m][2] + q;
        q = acc[m][3] * acc[m][3] + q;
#pragma unroll
        for (int st = 1; st <= 8; st <<= 1) {
#pragma unroll
            for (int r = 0; r < 4; ++r) {
                s[r] += __shfl_xor(s[r], st);
                q[r] += __shfl_xor(q[r], st);
            }
        }
        if (l16 == 0) {
#pragma unroll
            for (int r = 0; r < 4; ++r) {
                int row = m * 16 + g * 4 + r;
                *(f32x2*)(stats + row * 8 + w * 2) = (f32x2){s[r], q[r]};
            }
        }
    }
    __syncthreads();   // GEMM1 A-reads done everywhere; stats visible

    // ---- finish LN stats; apply LN + fast SiLU; write h' (over A region) ----
    f32x4 mu4[2], rs4[2];
#pragma unroll
    for (int m = 0; m < 2; ++m)
#pragma unroll
        for (int r = 0; r < 4; ++r) {
            int row = m * 16 + g * 4 + r;
            f32x4 a = *(const f32x4*)(stats + row * 8);
            f32x4 b = *(const f32x4*)(stats + row * 8 + 4);
            float S = (a[0] + a[2]) + (b[0] + b[2]);
            float Q = (a[1] + a[3]) + (b[1] + b[3]);
            float mm = S * (1.f / 256.f);
            float vv = fmaxf(Q * (1.f / 256.f) - mm * mm, 0.f);
            mu4[m][r] = mm;
            rs4[m][r] = __builtin_amdgcn_rsqf(vv + 1e-5f);
        }
    float g1v[4], bev[4];
#pragma unroll
    for (int n = 0; n < 4; ++n) {
        g1v[n] = g1[64 * w + 16 * n + l16];
        bev[n] = be1[64 * w + 16 * n + l16];
    }
#pragma unroll
    for (int m = 0; m < 2; ++m)
#pragma unroll
        for (int n = 0; n < 4; ++n) {
            f32x4 y = (acc[m][n] - mu4[m]) * rs4[m];
            y = y * g1v[n] + bev[n];
            int col = 64 * w + 16 * n + l16;
#pragma unroll
            for (int r = 0; r < 4; ++r) {
                float e = __builtin_amdgcn_exp2f(y[r] * -1.44269504f);
                float x = y[r] * __builtin_amdgcn_rcpf(1.f + e);   // SiLU
                int row = m * 16 + g * 4 + r;
                *(__bf16*)(lds + row * 528 + col * 2) = (__bf16)x;
            }
        }
    __syncthreads();   // h' complete

    // ---- GEMM2: [32,256] x [256,128], wave w owns cols [32w, 32w+32) ----
#pragma unroll
    for (int m = 0; m < 2; ++m)
#pragma unroll
        for (int n = 0; n < 2; ++n) acc2[m][n] = (f32x4){0.f, 0.f, 0.f, 0.f};
#pragma unroll
    for (int t = 0; t < 8; ++t) {
        bf16x8 af[2];
#pragma unroll
        for (int m = 0; m < 2; ++m)
            af[m] = *(const bf16x8*)(lds + (m * 16 + l16) * 528 + t * 64 + g * 16);
        const bf16x8* bp = pW2 + ((t * 8 + 2 * w) << 6) + lane;
#pragma unroll
        for (int n = 0; n < 2; ++n) {
            bf16x8 bf = bp[n << 6];
#pragma unroll
            for (int m = 0; m < 2; ++m)
                acc2[m][n] = mfma16x16x32(af[m], bf, acc2[m][n]);
        }
    }
}

// ---------------------------------------------------------------------------
// Edge kernel: 32 edges/block, 5 blocks/CU (proven best); bf16 node-table gathers
// ---------------------------------------------------------------------------
__global__ __launch_bounds__(256, 5) void edge_kernel(
    const __bf16* __restrict__ nbf, const float* __restrict__ ef,
    const int* __restrict__ eidx,
    const bf16x8* __restrict__ pW1, const bf16x8* __restrict__ pW2,
    const float* __restrict__ b1, const float* __restrict__ g1,
    const float* __restrict__ be1, const float* __restrict__ b2,
    float* __restrict__ out_edges) {
    __shared__ __align__(16) char lds[MR * 784 + MR * 32];   // 26112 B
    const int tid = threadIdx.x;
    const int eb = blockIdx.x * MR;

    {   // stage A = [nbf[snd] | nbf[rcv] | cvt(ef)]
        int row = tid >> 3, l8 = tid & 7;
        int e = eb + row;
        int snd = eidx[e], rcv = eidx[N_EDGES + e];
        snd = (snd < 0) ? 0 : (snd >= N_NODES ? N_NODES - 1 : snd);
        rcv = (rcv < 0) ? 0 : (rcv >= N_NODES ? N_NODES - 1 : rcv);
        const char* ps = (const char*)(nbf + (size_t)snd * DIM) + (l8 << 5);
        const char* pr = (const char*)(nbf + (size_t)rcv * DIM) + (l8 << 5);
        char* dst = lds + row * 784 + (l8 << 5);
        *(i32x4*)dst         = *(const i32x4*)ps;
        *(i32x4*)(dst + 16)  = *(const i32x4*)(ps + 16);
        *(i32x4*)(dst + 256) = *(const i32x4*)pr;
        *(i32x4*)(dst + 272) = *(const i32x4*)(pr + 16);
        const float* pe = ef + (size_t)e * DIM + (l8 << 4);
        f32x4 a0 = ((const f32x4*)pe)[0], a1 = ((const f32x4*)pe)[1];
        f32x4 a2 = ((const f32x4*)pe)[2], a3 = ((const f32x4*)pe)[3];
        *(bf16x8*)(dst + 512) = cvt2_bf16(a0, a1);
        *(bf16x8*)(dst + 528) = cvt2_bf16(a2, a3);
    }
    __syncthreads();

    f32x4 acc2[2][2];
    mlp_core<784, 12>(lds, pW1, pW2, b1, g1, be1, acc2);

    {   // epilogue: out = ef + (h' @ W2 + b2), direct from registers
        const int w = tid >> 6, lane = tid & 63;
        const int l16 = lane & 15, g = lane >> 4;
        float b2v[2];
#pragma unroll
        for (int n = 0; n < 2; ++n) b2v[n] = b2[32 * w + 16 * n + l16];
#pragma unroll
        for (int m = 0; m < 2; ++m)
#pragma unroll
            for (int n = 0; n < 2; ++n)
#pragma unroll
                for (int r = 0; r < 4; ++r) {
                    int e = eb + m * 16 + g * 4 + r;
                    int col = 32 * w + 16 * n + l16;
                    size_t off = (size_t)e * DIM + col;
                    out_edges[off] = acc2[m][n][r] + b2v[n] + ef[off];
                }
    }
}

// ---------------------------------------------------------------------------
// Node kernel: 32 nodes/block; bf16 node staging; CSR gather unrolled x2
// ---------------------------------------------------------------------------
__global__ __launch_bounds__(256, 5) void node_kernel(
    const float* __restrict__ node, const __bf16* __restrict__ nbf,
    const float* __restrict__ out_edges,
    const int* __restrict__ offsets, const int* __restrict__ eids,
    const bf16x8* __restrict__ pW1, const bf16x8* __restrict__ pW2,
    const float* __restrict__ b1, const float* __restrict__ g1,
    const float* __restrict__ be1, const float* __restrict__ b2,
    float* __restrict__ out_nodes) {
    __shared__ __align__(16) char lds[MR * 528 + MR * 32];   // 17920 B
    const int tid = threadIdx.x;
    const int nb = blockIdx.x * MR;

    {   // stage node_input = [nbf[n] | csr aggregate] -> bf16
        int row = tid >> 3, l8 = tid & 7;
        int n = nb + row;
        int nc = (n > N_NODES - 1) ? N_NODES - 1 : n;
        const char* pn = (const char*)(nbf + (size_t)nc * DIM) + (l8 << 5);
        char* dst = lds + row * 528 + (l8 << 5);
        *(i32x4*)dst        = *(const i32x4*)pn;
        *(i32x4*)(dst + 16) = *(const i32x4*)(pn + 16);
        // aggregate: lane owns 16 contiguous cols [l8*16, +16)
        float a[16];
#pragma unroll
        for (int j = 0; j < 16; ++j) a[j] = 0.f;
        int st = offsets[nc], en = offsets[nc + 1];
        int i = st;
#pragma unroll 1
        for (; i + 2 <= en; i += 2) {
            int e0 = eids[i], e1 = eids[i + 1];
            const float* er0 = out_edges + (size_t)e0 * DIM + (l8 << 4);
            const float* er1 = out_edges + (size_t)e1 * DIM + (l8 << 4);
            f32x4 u0 = ((const f32x4*)er0)[0], u1 = ((const f32x4*)er0)[1];
            f32x4 u2 = ((const f32x4*)er0)[2], u3 = ((const f32x4*)er0)[3];
            f32x4 v0 = ((const f32x4*)er1)[0], v1 = ((const f32x4*)er1)[1];
            f32x4 v2 = ((const f32x4*)er1)[2], v3 = ((const f32x4*)er1)[3];
#pragma unroll
            for (int k = 0; k < 4; ++k) {
                a[0 + k]  += u0[k] + v0[k];
                a[4 + k]  += u1[k] + v1[k];
                a[8 + k]  += u2[k] + v2[k];
                a[12 + k] += u3[k] + v3[k];
            }
        }
        if (i < en) {
            int e0 = eids[i];
            const float* er0 = out_edges + (size_t)e0 * DIM + (l8 << 4);
#pragma unroll
            for (int k = 0; k < 4; ++k) {
                f32x4 v = ((const f32x4*)er0)[k];
                a[k * 4 + 0] += v[0]; a[k * 4 + 1] += v[1];
                a[k * 4 + 2] += v[2]; a[k * 4 + 3] += v[3];
            }
        }
        bf16x8 o0, o1;
#pragma unroll
        for (int j = 0; j < 8; ++j) { o0[j] = (__bf16)a[j]; o1[j] = (__bf16)a[8 + j]; }
        int cbase = 16 + (l8 << 1);
        *(bf16x8*)(lds + row * 528 + (cbase << 4)) = o0;
        *(bf16x8*)(lds + row * 528 + ((cbase + 1) << 4)) = o1;
    }
    __syncthreads();

    f32x4 acc2[2][2];
    mlp_core<528, 8>(lds, pW1, pW2, b1, g1, be1, acc2);

    {   // epilogue: out = node + (h' @ W2 + b2), guarded
        const int w = tid >> 6, lane = tid & 63;
        const int l16 = lane & 15, g = lane >> 4;
        float b2v[2];
#pragma unroll
        for (int n = 0; n < 2; ++n) b2v[n] = b2[32 * w + 16 * n + l16];
#pragma unroll
        for (int m = 0; m < 2; ++m)
#pragma unroll
            for (int n = 0; n < 2; ++n)
#pragma unroll
                for (int r = 0; r < 4; ++r) {
                    int nd = nb + m * 16 + g * 4 + r;
                    if (nd < N_NODES) {
                        int col = 32 * w + 16 * n + l16;
                        size_t off = (size_t)nd * DIM + col;
                        out_nodes[off] = acc2[m][n][r] + b2v[n] + node[off];
                    }
                }
    }
}

// ---------------------------------------------------------------------------
extern "C" void kernel_launch(void* const* d_in, const int* in_sizes, int n_in,
                              void* d_out, int out_size, void* d_ws, size_t ws_size,
                              hipStream_t stream) {
    const float* node  = (const float*)d_in[0];
    const float* ef    = (const float*)d_in[1];
    const int*   eidx  = (const int*)d_in[2];
    const float* eW1   = (const float*)d_in[3];
    const float* eb1   = (const float*)d_in[4];
    const float* eg1   = (const float*)d_in[5];
    const float* ebt1  = (const float*)d_in[6];
    const float* eW2   = (const float*)d_in[7];
    const float* eb2   = (const float*)d_in[8];
    const float* nW1   = (const float*)d_in[9];
    const float* nb1   = (const float*)d_in[10];
    const float* ng1   = (const float*)d_in[11];
    const float* nbt1  = (const float*)d_in[12];
    const float* nW2   = (const float*)d_in[13];
    const float* nb2   = (const float*)d_in[14];

    char* ws = (char*)d_ws;
    int* counts  = (int*)ws;
    int* offsets = counts + 50016;
    int* cursor  = offsets + 50016;
    int* eids    = cursor + 50016;
    char* nbase = (char*)(eids + 600064);
    __bf16* nbf = (__bf16*)(((uintptr_t)nbase + 255) & ~(uintptr_t)255);   // 12.8 MB
    __bf16* peW1 = nbf + (size_t)N_NODES * DIM;
    __bf16* peW2 = peW1 + 384 * 256;
    __bf16* pnW1 = peW2 + 256 * 128;
    __bf16* pnW2 = pnW1 + 256 * 256;

    hipMemsetAsync(counts, 0, 50000 * sizeof(int), stream);
    nbf_kernel<<<(N_NODES * 16 + 255) / 256, 256, 0, stream>>>(node, nbf);
    pack_all_kernel<<<112, 256, 0, stream>>>(eW1, eW2, nW1, nW2, peW1, peW2, pnW1, pnW2);

    hist_kernel<<<(N_EDGES + 255) / 256, 256, 0, stream>>>(eidx, counts);
    scan_kernel<<<1, 1024, 0, stream>>>(counts, offsets, cursor);
    scatter_kernel<<<(N_EDGES + 255) / 256, 256, 0, stream>>>(eidx, cursor, eids);

    float* out_nodes = (float*)d_out;
    float* out_edges = out_nodes + (size_t)N_NODES * DIM;

    edge_kernel<<<N_EDGES / MR, 256, 0, stream>>>(
        nbf, ef, eidx, (const bf16x8*)peW1, (const bf16x8*)peW2,
        eb1, eg1, ebt1, eb2, out_edges);
    node_kernel<<<(N_NODES + MR - 1) / MR, 256, 0, stream>>>(
        node, nbf, out_edges, offsets, eids, (const bf16x8*)pnW1, (const bf16x8*)pnW2,
        nb1, ng1, nbt1, nb2, out_nodes);
}